// Round 14
// baseline (515.265 us; speedup 1.0000x reference)
//
#include <hip/hip_runtime.h>
#include <hip/hip_cooperative_groups.h>

namespace cg = cooperative_groups;

#define Df 64
#define NN 10000
#define EE 160000
#define RR 16
#define CC 512
#define CAP1 128
#define CAP2 2048
#define NGEMM 157            // ceil(10000/64) GEMM tiles
#define NAGG 2500            // 10000/4 agg vblocks (wave per node)
#define NEDG 625             // 160000/256 edge vblocks
#define NSLF 40              // ceil(10000/256) self-merge vblocks
#define ND1B 512             // 16 * (CAP1/4) delta1 vblocks
#define ND2B 8192            // 16 * (CAP2/4) delta2 vblocks
#define NTHR 256

// ---------------- static device scratch ----------------
__device__ float g_h0[NN * Df];
__device__ float g_h1b[NN * Df];
__device__ float g_h2b[NN * Df];
__device__ float g_agg[NN * Df];
__device__ float g_zrow[Df];
__device__ __align__(16) float g_W20[128 * Df];   // [Ws0;Wn0] row-major [k][d]
__device__ __align__(16) float g_W21[128 * Df];   // [Ws1;Wn1]
__device__ int g_cntI[NN], g_rowI[NN + 1], g_posI[NN], g_csrI[EE];
__device__ int g_m1mask[NN], g_m2mask[NN];
__device__ int g_mark1[RR][NN], g_mark2[RR][NN];  // slot+1 maps (fully rewritten)
__device__ int g_n1[RR], g_n2[RR];
__device__ int g_list1[RR][CAP1], g_list2[RR][CAP2];
__device__ float g_d1[RR][CAP1][Df];
__device__ float g_d2[RR][CAP2][Df];
__device__ float g_score[RR * CC];

// ---------------- single-block CSR scan (256 thr) ----------------
__device__ void scan_csr(void) {
    int t = threadIdx.x;
    int lane = t & 63, wv = t >> 6;
    const int PER = 40;
    int base = t * PER;
    int loc = 0;
    for (int k = 0; k < PER; k++) { int v = base + k; if (v < NN) loc += g_cntI[v]; }
    int sc = loc;
#pragma unroll
    for (int off = 1; off < 64; off <<= 1) { int x = __shfl_up(sc, off, 64); if (lane >= off) sc += x; }
    __shared__ int wsumS[4];
    if (lane == 63) wsumS[wv] = sc;
    __syncthreads();
    if (t == 0) { int a = 0; for (int w2 = 0; w2 < 4; w2++) { int x = wsumS[w2]; wsumS[w2] = a; a += x; } }
    __syncthreads();
    int run = wsumS[wv] + (sc - loc);
    for (int k = 0; k < PER; k++) {
        int v = base + k;
        if (v < NN) { g_rowI[v] = run; g_posI[v] = run; run += g_cntI[v]; }
    }
    if (t == 255) g_rowI[NN] = run;
    __syncthreads();
}

// ---------------- mask-bit compaction (256 thr) ----------------
__device__ void compact256(const int* __restrict__ maskArr, int bit,
                           int* mark, int* list, int* nout, int cap) {
    int t = threadIdx.x;
    int lane = t & 63, wv = t >> 6;
    const int PER = 40;
    int base = t * PER;
    int loc = 0;
    for (int k = 0; k < PER; k++) { int v = base + k; if (v < NN) loc += (maskArr[v] >> bit) & 1; }
    int sc = loc;
#pragma unroll
    for (int off = 1; off < 64; off <<= 1) { int x = __shfl_up(sc, off, 64); if (lane >= off) sc += x; }
    __shared__ int wsumC[4];
    if (lane == 63) wsumC[wv] = sc;
    __syncthreads();
    if (t == 0) { int a = 0; for (int w2 = 0; w2 < 4; w2++) { int x = wsumC[w2]; wsumC[w2] = a; a += x; } }
    __syncthreads();
    int run = wsumC[wv] + (sc - loc);
    for (int k = 0; k < PER; k++) {
        int v = base + k;
        if (v < NN) {
            int f = (maskArr[v] >> bit) & 1;
            if (f && run < cap) { list[run] = v; mark[v] = run + 1; }
            else mark[v] = 0;
            run += f;
        }
    }
    if (t == 255) *nout = (run < cap) ? run : cap;
    __syncthreads();
}

// ---------------- agg (wave per node, 4x unrolled gather) ----------------
__device__ void agg_quad(const float* __restrict__ hin, int b, int tid) {
    int lane = tid & 63, w = tid >> 6;
    int n = b * 4 + w;
    int a0 = g_rowI[n], a1 = g_rowI[n + 1];
    float s0 = 0.f, s1 = 0.f, s2 = 0.f, s3 = 0.f;
    int i = a0;
    for (; i + 4 <= a1; i += 4) {
        int c0 = g_csrI[i], c1 = g_csrI[i + 1], c2 = g_csrI[i + 2], c3 = g_csrI[i + 3];
        s0 += hin[c0 * Df + lane];
        s1 += hin[c1 * Df + lane];
        s2 += hin[c2 * Df + lane];
        s3 += hin[c3 * Df + lane];
    }
    for (; i < a1; i++) s0 += hin[g_csrI[i] * Df + lane];
    float s = (s0 + s1) + (s2 + s3);
    g_agg[n * Df + lane] = s / fmaxf((float)(a1 - a0), 1.f);
}

// ---------------- tiled GEMM (64 nodes x 64 dims, K=128) ----------------
__device__ void gemm_tile(const float* __restrict__ hin, float* __restrict__ hout,
                          const float* __restrict__ W2, const float* __restrict__ bias,
                          int m0, int tid, char* smem) {
    float (*Xs)[68] = (float(*)[68])smem;
    float (*Wl)[64] = (float(*)[64])(smem + 8704);
    int tx = tid & 15, ty = tid >> 4;
    float acc[4][4];
#pragma unroll
    for (int i = 0; i < 4; i++)
#pragma unroll
        for (int j = 0; j < 4; j++) acc[i][j] = 0.f;

    for (int c = 0; c < 4; c++) {
        const float* src = (c < 2) ? hin : g_agg;
        int kb = (c & 1) * 32;
        int kbase = c * 32;
#pragma unroll
        for (int rep = 0; rep < 2; rep++) {
            int slot = tid + rep * 256;
            int m = slot >> 3, q = slot & 7;
            int n = m0 + m;
            float4 v = make_float4(0.f, 0.f, 0.f, 0.f);
            if (n < NN) v = *(const float4*)&src[n * Df + kb + q * 4];
            Xs[q * 4 + 0][m] = v.x; Xs[q * 4 + 1][m] = v.y;
            Xs[q * 4 + 2][m] = v.z; Xs[q * 4 + 3][m] = v.w;
            int k = slot >> 4, dq = slot & 15;
            *(float4*)&Wl[k][dq * 4] = *(const float4*)&W2[(kbase + k) * Df + dq * 4];
        }
        __syncthreads();
#pragma unroll
        for (int k = 0; k < 32; k++) {
            float4 x4 = *(const float4*)&Xs[k][ty * 4];
            float4 w4 = *(const float4*)&Wl[k][tx * 4];
            float xs[4] = {x4.x, x4.y, x4.z, x4.w};
            float ws[4] = {w4.x, w4.y, w4.z, w4.w};
#pragma unroll
            for (int i = 0; i < 4; i++)
#pragma unroll
                for (int j = 0; j < 4; j++) acc[i][j] += xs[i] * ws[j];
        }
        __syncthreads();
    }
    float4 b4 = *(const float4*)&bias[tx * 4];
    float bb[4] = {b4.x, b4.y, b4.z, b4.w};
#pragma unroll
    for (int i = 0; i < 4; i++) {
        int n = m0 + ty * 4 + i;
        if (n < NN) {
            float4 hv = *(const float4*)&hin[n * Df + tx * 4];
            float4 o;
            o.x = fmaxf(acc[i][0] + bb[0], 0.f) + hv.x;
            o.y = fmaxf(acc[i][1] + bb[1], 0.f) + hv.y;
            o.z = fmaxf(acc[i][2] + bb[2], 0.f) + hv.z;
            o.w = fmaxf(acc[i][3] + bb[3], 0.f) + hv.w;
            *(float4*)&hout[n * Df + tx * 4] = o;
        }
    }
}

// ---------------- delta1 (4 slots/vblock, wave per slot) ----------------
__device__ void delta1_blk(int rel, int tid, const int* __restrict__ removal,
                           const float* __restrict__ Ws, const float* __restrict__ Wn,
                           const float* __restrict__ bias, char* smem) {
    float* s_h = (float*)smem;                   // [4][Df]
    float* s_a = s_h + 4 * Df;
    int ri = rel >> 5, y = rel & 31;
    int lane = tid & 63, w = tid >> 6;
    int j = y * 4 + w;
    if (j >= g_n1[ri]) return;
    int v = g_list1[ri][j];
    int r = removal[ri];
    float p0s = 0.f, p1s = 0.f, p2s = 0.f, p3s = 0.f; int cnt = 0;
    if (v != r) {
        int e0 = g_rowI[v], e1 = g_rowI[v + 1];
        int i = e0;
        for (; i + 4 <= e1; i += 4) {
            int c0 = g_csrI[i], c1 = g_csrI[i + 1], c2 = g_csrI[i + 2], c3 = g_csrI[i + 3];
            const float* p0 = (c0 == r) ? g_zrow : &g_h0[c0 * Df];
            const float* p1 = (c1 == r) ? g_zrow : &g_h0[c1 * Df];
            const float* p2 = (c2 == r) ? g_zrow : &g_h0[c2 * Df];
            const float* p3 = (c3 == r) ? g_zrow : &g_h0[c3 * Df];
            p0s += p0[lane]; p1s += p1[lane]; p2s += p2[lane]; p3s += p3[lane];
            cnt += (c0 != r) + (c1 != r) + (c2 != r) + (c3 != r);
        }
        for (; i < e1; i++) {
            int c = g_csrI[i];
            const float* p = (c == r) ? g_zrow : &g_h0[c * Df];
            p0s += p[lane]; cnt += (c != r);
        }
    }
    float aggd = (p0s + p1s) + (p2s + p3s);
    float hv = g_h0[v * Df + lane];
    s_h[w * Df + lane] = hv;
    s_a[w * Df + lane] = aggd / fmaxf((float)cnt, 1.f);
    float acc = bias[lane];
#pragma unroll 16
    for (int k = 0; k < Df; k++)
        acc += s_h[w * Df + k] * Ws[k * Df + lane] + s_a[w * Df + k] * Wn[k * Df + lane];
    g_d1[ri][j][lane] = fmaxf(acc, 0.f) + hv;
}

// ---------------- delta2 (4 slots/vblock, wave per slot) ----------------
__device__ void delta2_blk(int rel, int tid, const int* __restrict__ removal,
                           const float* __restrict__ Ws, const float* __restrict__ Wn,
                           const float* __restrict__ bias, char* smem) {
    float* s_h = (float*)smem;
    float* s_a = s_h + 4 * Df;
    int ri = rel >> 9, y = rel & 511;
    int lane = tid & 63, w = tid >> 6;
    int j = y * 4 + w;
    if (j >= g_n2[ri]) return;
    int v = g_list2[ri][j];
    int r = removal[ri];
    const int* mk1 = g_mark1[ri];
    float p0s = 0.f, p1s = 0.f, p2s = 0.f, p3s = 0.f; int cnt = 0;
    if (v != r) {
        int e0 = g_rowI[v], e1 = g_rowI[v + 1];
        int i = e0;
        for (; i + 4 <= e1; i += 4) {
            int c0 = g_csrI[i], c1 = g_csrI[i + 1], c2 = g_csrI[i + 2], c3 = g_csrI[i + 3];
            int m0 = mk1[c0], m1 = mk1[c1], m2 = mk1[c2], m3 = mk1[c3];
            const float* p0 = (c0 == r) ? g_zrow : (m0 > 0 ? &g_d1[ri][m0 - 1][0] : &g_h1b[c0 * Df]);
            const float* p1 = (c1 == r) ? g_zrow : (m1 > 0 ? &g_d1[ri][m1 - 1][0] : &g_h1b[c1 * Df]);
            const float* p2 = (c2 == r) ? g_zrow : (m2 > 0 ? &g_d1[ri][m2 - 1][0] : &g_h1b[c2 * Df]);
            const float* p3 = (c3 == r) ? g_zrow : (m3 > 0 ? &g_d1[ri][m3 - 1][0] : &g_h1b[c3 * Df]);
            p0s += p0[lane]; p1s += p1[lane]; p2s += p2[lane]; p3s += p3[lane];
            cnt += (c0 != r) + (c1 != r) + (c2 != r) + (c3 != r);
        }
        for (; i < e1; i++) {
            int c = g_csrI[i];
            int m = mk1[c];
            const float* p = (c == r) ? g_zrow : (m > 0 ? &g_d1[ri][m - 1][0] : &g_h1b[c * Df]);
            p0s += p[lane]; cnt += (c != r);
        }
    }
    float aggd = (p0s + p1s) + (p2s + p3s);
    int mv = mk1[v];
    float hv = (mv > 0) ? g_d1[ri][mv - 1][lane] : g_h1b[v * Df + lane];
    s_h[w * Df + lane] = hv;
    s_a[w * Df + lane] = aggd / fmaxf((float)cnt, 1.f);
    float acc = bias[lane];
#pragma unroll 16
    for (int k = 0; k < Df; k++)
        acc += s_h[w * Df + k] * Ws[k * Df + lane] + s_a[w * Df + k] * Wn[k * Df + lane];
    g_d2[ri][j][lane] = fmaxf(acc, 0.f) + hv;
}

// ---------------- score GEMM (64 edges x 64 dims per vblock) ----------------
__device__ void score_blk(int wb, int tid, const int* __restrict__ conn,
                          const int* __restrict__ removal, const int* __restrict__ esrc,
                          const int* __restrict__ edst, const float* __restrict__ We,
                          const float* __restrict__ be, const float* __restrict__ Wsc,
                          const float* __restrict__ bsc, char* smem) {
    const float** ptrs = (const float**)smem;                  // 128 ptrs = 1024 B
    float (*Xs)[68] = (float(*)[68])(smem + 1024);
    float (*Wl)[64] = (float(*)[64])(smem + 1024 + 8704);
    float* su = (float*)(smem + 1024 + 8704 + 8192);
    int e0 = wb * 64;
    int ri = e0 >> 9;

    if (tid < 64) {
        int e = conn[e0 + tid];
        int s = esrc[e], d = edst[e];
        int ms = g_mark2[ri][s], md = g_mark2[ri][d];
        ptrs[tid]      = (ms > 0) ? &g_d2[ri][ms - 1][0] : &g_h2b[s * Df];
        ptrs[64 + tid] = (md > 0) ? &g_d2[ri][md - 1][0] : &g_h2b[d * Df];
    } else if (tid < 128) {
        int lane = tid & 63;
        float up = g_h0[removal[ri] * Df + lane] * Wsc[lane];
#pragma unroll
        for (int off = 32; off > 0; off >>= 1) up += __shfl_xor(up, off, 64);
        if (lane == 0) *su = up;
    }
    __syncthreads();

    int tx = tid & 15, ty = tid >> 4;
    float acc[4][4];
#pragma unroll
    for (int i = 0; i < 4; i++)
#pragma unroll
        for (int j = 0; j < 4; j++) acc[i][j] = 0.f;

    for (int c = 0; c < 4; c++) {
        int kb = (c & 1) * 32;
#pragma unroll
        for (int rep = 0; rep < 2; rep++) {
            int slot = tid + rep * 256;
            int m = slot >> 3, q = slot & 7;
            const float* p = ((c < 2) ? ptrs[m] : ptrs[64 + m]) + kb + q * 4;
            float4 v = *(const float4*)p;
            Xs[q * 4 + 0][m] = v.x; Xs[q * 4 + 1][m] = v.y;
            Xs[q * 4 + 2][m] = v.z; Xs[q * 4 + 3][m] = v.w;
            int k = slot >> 4, dq = slot & 15;
            *(float4*)&Wl[k][dq * 4] = *(const float4*)&We[(c * 32 + k) * Df + dq * 4];
        }
        __syncthreads();
#pragma unroll
        for (int k = 0; k < 32; k++) {
            float4 x4 = *(const float4*)&Xs[k][ty * 4];
            float4 w4 = *(const float4*)&Wl[k][tx * 4];
            float xs[4] = {x4.x, x4.y, x4.z, x4.w};
            float ws[4] = {w4.x, w4.y, w4.z, w4.w};
#pragma unroll
            for (int i = 0; i < 4; i++)
#pragma unroll
                for (int j = 0; j < 4; j++) acc[i][j] += xs[i] * ws[j];
        }
        __syncthreads();
    }

    float4 be4 = *(const float4*)&be[tx * 4];
    float4 w2  = *(const float4*)&Wsc[Df + tx * 4];
    float bb[4] = {be4.x, be4.y, be4.z, be4.w};
    float ww[4] = {w2.x, w2.y, w2.z, w2.w};
    float sb = *su + bsc[0];
#pragma unroll
    for (int i = 0; i < 4; i++) {
        float part = 0.f;
#pragma unroll
        for (int j = 0; j < 4; j++) part += fmaxf(acc[i][j] + bb[j], 0.f) * ww[j];
#pragma unroll
        for (int off = 1; off < 16; off <<= 1) part += __shfl_xor(part, off, 64);
        if (tx == 0) g_score[e0 + ty * 4 + i] = part + sb;
    }
}

// ---------------- softmax (one vblock per removal) ----------------
__device__ void softmax_blk(int r, int tid, float* __restrict__ out, char* smem) {
    float* red = (float*)smem;
    float v0 = g_score[r * CC + tid];
    float v1 = g_score[r * CC + 256 + tid];
    red[tid] = fmaxf(v0, v1);
    __syncthreads();
    for (int off = 128; off > 0; off >>= 1) {
        if (tid < off) red[tid] = fmaxf(red[tid], red[tid + off]);
        __syncthreads();
    }
    float mx = red[0];
    __syncthreads();
    float e0 = expf(v0 - mx), e1 = expf(v1 - mx);
    red[tid] = e0 + e1;
    __syncthreads();
    for (int off = 128; off > 0; off >>= 1) {
        if (tid < off) red[tid] += red[tid + off];
        __syncthreads();
    }
    float inv = 1.f / red[0];
    out[r * CC + tid] = e0 * inv;
    out[r * CC + 256 + tid] = e1 * inv;
}

// ================= cooperative mega kernel (grid-size agnostic) =================
__global__ __launch_bounds__(256, 4) void k_mega(
        const float* __restrict__ coords, const float* __restrict__ We,
        const float* __restrict__ be,
        const float* __restrict__ Ws0, const float* __restrict__ Wn0,
        const float* __restrict__ b0,
        const float* __restrict__ Ws1, const float* __restrict__ Wn1,
        const float* __restrict__ b1,
        const float* __restrict__ Wedge, const float* __restrict__ bedge,
        const float* __restrict__ Wsc, const float* __restrict__ bsc,
        const int* __restrict__ esrc, const int* __restrict__ edst,
        const int* __restrict__ removal, const int* __restrict__ conn,
        float* __restrict__ out) {
    __shared__ __align__(16) char smem[18048];
    cg::grid_group grid = cg::this_grid();
    const int tid = threadIdx.x;
    const int bid = blockIdx.x;
    const int nb = gridDim.x;
    const int gt = bid * NTHR + tid;
    const int gstride = nb * NTHR;

    // ---- P0: init ----
    for (int i = gt; i < NN * Df; i += gstride) {
        int n = i >> 6, d = i & 63;
        g_h0[i] = coords[2 * n] * We[d] + coords[2 * n + 1] * We[Df + d] + be[d];
    }
    for (int i = gt; i < NN; i += gstride) { g_cntI[i] = 0; g_m1mask[i] = 0; g_m2mask[i] = 0; }
    if (gt < Df) g_zrow[gt] = 0.f;
    for (int i = gt; i < 8192; i += gstride) {
        int k = i >> 6, d = i & 63;
        g_W20[i] = (k < 64) ? Ws0[k * 64 + d] : Wn0[(k - 64) * 64 + d];
        g_W21[i] = (k < 64) ? Ws1[k * 64 + d] : Wn1[(k - 64) * 64 + d];
    }
    grid.sync();

    // ---- P1: hist | flag1 | self1 ----
    for (int e = gt; e < EE; e += gstride) {
        atomicAdd(&g_cntI[edst[e]], 1);
        int s = esrc[e];
        int m = 0;
#pragma unroll
        for (int ri = 0; ri < RR; ri++)
            if (s == removal[ri]) m |= (1 << ri);
        if (m) atomicOr(&g_m1mask[edst[e]], m);
    }
    if (gt < RR) atomicOr(&g_m1mask[removal[gt]], 1 << gt);
    grid.sync();

    // ---- P2: scan | compact1 ----
    if (bid == 0) scan_csr();
    else if (bid <= RR) {
        int ri = bid - 1;
        compact256(g_m1mask, ri, g_mark1[ri], g_list1[ri], &g_n1[ri], CAP1);
    }
    grid.sync();

    // ---- P3: fill | flag2-edges | flag2-self ----
    for (int wb = bid; wb < NEDG + NEDG + NSLF; wb += nb) {
        if (wb < NEDG) {
            int e = wb * 256 + tid;
            if (e < EE) {
                int p = atomicAdd(&g_posI[edst[e]], 1);
                g_csrI[p] = esrc[e];
            }
        } else if (wb < NEDG + NEDG) {
            int e = (wb - NEDG) * 256 + tid;
            if (e < EE) {
                int m = g_m1mask[esrc[e]];
                if (m) atomicOr(&g_m2mask[edst[e]], m);
            }
        } else {
            int v = (wb - 2 * NEDG) * 256 + tid;
            if (v < NN) {
                int m = g_m1mask[v];
                if (m) atomicOr(&g_m2mask[v], m);
            }
        }
    }
    grid.sync();

    // ---- P4: compact2 | delta1 | agg0 ----
    for (int wb = bid; wb < RR + ND1B + NAGG; wb += nb) {
        if (wb < RR) compact256(g_m2mask, wb, g_mark2[wb], g_list2[wb], &g_n2[wb], CAP2);
        else if (wb < RR + ND1B) delta1_blk(wb - RR, tid, removal, Ws0, Wn0, b0, smem);
        else agg_quad(g_h0, wb - RR - ND1B, tid);
    }
    grid.sync();

    // ---- P5: gemm0 ----
    for (int wb = bid; wb < NGEMM; wb += nb)
        gemm_tile(g_h0, g_h1b, g_W20, b0, wb * 64, tid, smem);
    grid.sync();

    // ---- P6: agg1 | delta2 ----
    for (int wb = bid; wb < NAGG + ND2B; wb += nb) {
        if (wb < NAGG) agg_quad(g_h1b, wb, tid);
        else delta2_blk(wb - NAGG, tid, removal, Ws1, Wn1, b1, smem);
    }
    grid.sync();

    // ---- P7: gemm1 ----
    for (int wb = bid; wb < NGEMM; wb += nb)
        gemm_tile(g_h1b, g_h2b, g_W21, b1, wb * 64, tid, smem);
    grid.sync();

    // ---- P8: score ----
    for (int wb = bid; wb < RR * CC / 64; wb += nb)
        score_blk(wb, tid, conn, removal, esrc, edst, Wedge, bedge, Wsc, bsc, smem);
    grid.sync();

    // ---- P9: softmax ----
    for (int wb = bid; wb < RR; wb += nb)
        softmax_blk(wb, tid, out, smem);
}

// ================= fallback multi-kernel path (round-12 structure) =================
__global__ void kf_init(const float* __restrict__ coords, const float* __restrict__ We,
                        const float* __restrict__ be, const float* __restrict__ Ws0,
                        const float* __restrict__ Wn0, const float* __restrict__ Ws1,
                        const float* __restrict__ Wn1) {
    int i = blockIdx.x * 256 + threadIdx.x;
    if (i < NN * Df) {
        int n = i >> 6, d = i & 63;
        g_h0[i] = coords[2 * n] * We[d] + coords[2 * n + 1] * We[Df + d] + be[d];
    }
    if (i < NN) { g_cntI[i] = 0; g_m1mask[i] = 0; g_m2mask[i] = 0; }
    if (i < Df) g_zrow[i] = 0.f;
    if (i < 8192) {
        int k = i >> 6, d = i & 63;
        g_W20[i] = (k < 64) ? Ws0[k * 64 + d] : Wn0[(k - 64) * 64 + d];
        g_W21[i] = (k < 64) ? Ws1[k * 64 + d] : Wn1[(k - 64) * 64 + d];
    }
}

__global__ void kf_edge1(const int* __restrict__ esrc, const int* __restrict__ edst,
                         const int* __restrict__ removal) {
    int e = blockIdx.x * 256 + threadIdx.x;
    if (e < EE) {
        int d = edst[e];
        atomicAdd(&g_cntI[d], 1);
        int s = esrc[e];
        int m = 0;
#pragma unroll
        for (int ri = 0; ri < RR; ri++)
            if (s == removal[ri]) m |= (1 << ri);
        if (m) atomicOr(&g_m1mask[d], m);
    }
    if (blockIdx.x == 0 && threadIdx.x < RR)
        atomicOr(&g_m1mask[removal[threadIdx.x]], 1 << threadIdx.x);
}

__global__ __launch_bounds__(256) void kf_scan16() {
    int b = blockIdx.x;
    if (b == 0) scan_csr();
    else {
        int ri = b - 1;
        compact256(g_m1mask, ri, g_mark1[ri], g_list1[ri], &g_n1[ri], CAP1);
    }
}

__global__ void kf_fill2(const int* __restrict__ esrc, const int* __restrict__ edst) {
    int b = blockIdx.x, tid = threadIdx.x;
    if (b < NEDG) {
        int e = b * 256 + tid;
        if (e < EE) {
            int p = atomicAdd(&g_posI[edst[e]], 1);
            g_csrI[p] = esrc[e];
        }
    } else if (b < 2 * NEDG) {
        int e = (b - NEDG) * 256 + tid;
        if (e < EE) {
            int m = g_m1mask[esrc[e]];
            if (m) atomicOr(&g_m2mask[edst[e]], m);
        }
    } else {
        int v = (b - 2 * NEDG) * 256 + tid;
        if (v < NN) {
            int m = g_m1mask[v];
            if (m) atomicOr(&g_m2mask[v], m);
        }
    }
}

__global__ __launch_bounds__(256) void kf_p4(const int* __restrict__ removal,
        const float* __restrict__ Ws0, const float* __restrict__ Wn0,
        const float* __restrict__ b0) {
    __shared__ __align__(16) char smem[2048];
    int b = blockIdx.x, tid = threadIdx.x;
    if (b < RR) compact256(g_m2mask, b, g_mark2[b], g_list2[b], &g_n2[b], CAP2);
    else if (b < RR + ND1B) delta1_blk(b - RR, tid, removal, Ws0, Wn0, b0, smem);
    else agg_quad(g_h0, b - RR - ND1B, tid);
}

__global__ __launch_bounds__(256) void kf_gemm(int layer, const float* __restrict__ bias) {
    __shared__ __align__(16) char smem[16896];
    const float* hin = layer ? g_h1b : g_h0;
    float* hout      = layer ? g_h2b : g_h1b;
    const float* W2  = layer ? g_W21 : g_W20;
    gemm_tile(hin, hout, W2, bias, blockIdx.x * 64, threadIdx.x, smem);
}

__global__ __launch_bounds__(256) void kf_p6(const int* __restrict__ removal,
        const float* __restrict__ Ws1, const float* __restrict__ Wn1,
        const float* __restrict__ b1) {
    __shared__ __align__(16) char smem[2048];
    int b = blockIdx.x, tid = threadIdx.x;
    if (b < NAGG) agg_quad(g_h1b, b, tid);
    else delta2_blk(b - NAGG, tid, removal, Ws1, Wn1, b1, smem);
}

__global__ __launch_bounds__(256) void kf_score(const int* __restrict__ conn,
        const int* __restrict__ removal, const int* __restrict__ esrc,
        const int* __restrict__ edst, const float* __restrict__ We,
        const float* __restrict__ be, const float* __restrict__ Wsc,
        const float* __restrict__ bsc) {
    __shared__ __align__(16) char smem[18048];
    score_blk(blockIdx.x, threadIdx.x, conn, removal, esrc, edst, We, be, Wsc, bsc, smem);
}

__global__ void kf_softmax(float* __restrict__ out) {
    __shared__ __align__(16) char smem[1024];
    softmax_blk(blockIdx.x, threadIdx.x, out, smem);
}

extern "C" void kernel_launch(void* const* d_in, const int* in_sizes, int n_in,
                              void* d_out, int out_size, void* d_ws, size_t ws_size,
                              hipStream_t stream) {
    const float* coords   = (const float*)d_in[0];
    const float* W_emb    = (const float*)d_in[1];
    const float* b_emb    = (const float*)d_in[2];
    const float* W_self0  = (const float*)d_in[3];
    const float* W_neigh0 = (const float*)d_in[4];
    const float* b_gnn0   = (const float*)d_in[5];
    const float* W_self1  = (const float*)d_in[6];
    const float* W_neigh1 = (const float*)d_in[7];
    const float* b_gnn1   = (const float*)d_in[8];
    const float* W_edge   = (const float*)d_in[9];
    const float* b_edge   = (const float*)d_in[10];
    const float* W_score  = (const float*)d_in[11];
    const float* b_score  = (const float*)d_in[12];
    const int* esrc       = (const int*)d_in[13];
    const int* edst       = (const int*)d_in[14];
    const int* removal    = (const int*)d_in[15];
    const int* conn       = (const int*)d_in[16];
    float* outp           = (float*)d_out;

    // ---- try cooperative mega-kernel with runtime-queried grid ----
    hipError_t err = hipErrorUnknown;
    int dev = 0;
    (void)hipGetDevice(&dev);
    hipDeviceProp_t props;
    int numCU = 0;
    if (hipGetDeviceProperties(&props, dev) == hipSuccess) numCU = props.multiProcessorCount;
    int maxb = 0;
    hipError_t oe = hipOccupancyMaxActiveBlocksPerMultiprocessor(
        &maxb, reinterpret_cast<const void*>(k_mega), NTHR, 0);
    int nblk = (oe == hipSuccess && maxb > 0 && numCU > 0) ? maxb * numCU : 0;
    if (nblk > 1024) nblk = 1024;
    if (nblk >= 64) {
        void* args[] = {
            (void*)&coords, (void*)&W_emb, (void*)&b_emb,
            (void*)&W_self0, (void*)&W_neigh0, (void*)&b_gnn0,
            (void*)&W_self1, (void*)&W_neigh1, (void*)&b_gnn1,
            (void*)&W_edge, (void*)&b_edge, (void*)&W_score, (void*)&b_score,
            (void*)&esrc, (void*)&edst, (void*)&removal, (void*)&conn,
            (void*)&outp
        };
        err = hipLaunchCooperativeKernel(reinterpret_cast<const void*>(k_mega),
                                         dim3(nblk), dim3(NTHR), args, 0, stream);
    }
    if (err == hipSuccess) return;
    (void)hipGetLastError();                     // clear sticky error

    // ---- fallback: proven multi-kernel path ----
    kf_init<<<2500, 256, 0, stream>>>(coords, W_emb, b_emb, W_self0, W_neigh0,
                                      W_self1, W_neigh1);
    kf_edge1<<<NEDG, 256, 0, stream>>>(esrc, edst, removal);
    kf_scan16<<<RR + 1, 256, 0, stream>>>();
    kf_fill2<<<2 * NEDG + NSLF, 256, 0, stream>>>(esrc, edst);
    kf_p4<<<RR + ND1B + NAGG, 256, 0, stream>>>(removal, W_self0, W_neigh0, b_gnn0);
    kf_gemm<<<NGEMM, 256, 0, stream>>>(0, b_gnn0);
    kf_p6<<<NAGG + ND2B, 256, 0, stream>>>(removal, W_self1, W_neigh1, b_gnn1);
    kf_gemm<<<NGEMM, 256, 0, stream>>>(1, b_gnn1);
    kf_score<<<RR * CC / 64, 256, 0, stream>>>(conn, removal, esrc, edst,
                                               W_edge, b_edge, W_score, b_score);
    kf_softmax<<<RR, 256, 0, stream>>>(outp);
}

// Round 15
// 126.513 us; speedup vs baseline: 4.0728x; 4.0728x over previous
//
#include <hip/hip_runtime.h>

#define Df 64
#define NN 10000
#define EE 160000
#define RR 16
#define CC 512
#define CAP1 128
#define CAP2 2048
#define BST 128              // bucket stride (max in-degree supported)
#define NGEMM 157            // ceil(10000/64) GEMM tiles
#define NAGG 2500            // 10000/4 agg blocks (wave per node)
#define NEDG 625             // 160000/256 edge blocks
#define NSLF 40              // ceil(10000/256) self-merge blocks
#define ND1B 512             // 16 * (CAP1/4) delta1 blocks
#define ND2B 8192            // 16 * (CAP2/4) delta2 blocks

// ---------------- static device scratch ----------------
__device__ float g_h0[NN * Df];
__device__ float g_h1b[NN * Df];
__device__ float g_h2b[NN * Df];
__device__ float g_agg[NN * Df];
__device__ float g_zrow[Df];
__device__ __align__(16) float g_W20[128 * Df];   // [Ws0;Wn0] row-major [k][d]
__device__ __align__(16) float g_W21[128 * Df];   // [Ws1;Wn1]
__device__ int g_deg[NN];
__device__ __align__(16) int g_bkt[NN * BST];     // in-neighbor buckets
__device__ int g_m1mask[NN], g_m2mask[NN];
__device__ int g_mark1[RR][NN], g_mark2[RR][NN];  // slot+1 maps (fully rewritten)
__device__ int g_n1[RR], g_n2[RR];
__device__ int g_list1[RR][CAP1], g_list2[RR][CAP2];
__device__ float g_d1[RR][CAP1][Df];
__device__ float g_d2[RR][CAP2][Df];
__device__ float g_score[RR * CC];

// ---------------- mask-bit compaction (256 thr) ----------------
__device__ void compact256(const int* __restrict__ maskArr, int bit,
                           int* mark, int* list, int* nout, int cap) {
    int t = threadIdx.x;
    int lane = t & 63, wv = t >> 6;
    const int PER = 40;
    int base = t * PER;
    int loc = 0;
    for (int k = 0; k < PER; k++) { int v = base + k; if (v < NN) loc += (maskArr[v] >> bit) & 1; }
    int sc = loc;
#pragma unroll
    for (int off = 1; off < 64; off <<= 1) { int x = __shfl_up(sc, off, 64); if (lane >= off) sc += x; }
    __shared__ int wsumC[4];
    if (lane == 63) wsumC[wv] = sc;
    __syncthreads();
    if (t == 0) { int a = 0; for (int w2 = 0; w2 < 4; w2++) { int x = wsumC[w2]; wsumC[w2] = a; a += x; } }
    __syncthreads();
    int run = wsumC[wv] + (sc - loc);
    for (int k = 0; k < PER; k++) {
        int v = base + k;
        if (v < NN) {
            int f = (maskArr[v] >> bit) & 1;
            if (f && run < cap) { list[run] = v; mark[v] = run + 1; }
            else mark[v] = 0;
            run += f;
        }
    }
    if (t == 255) *nout = (run < cap) ? run : cap;
    __syncthreads();
}

// ---------------- agg: wave per node, 8x unrolled bucket gather ----------------
__device__ void agg8(const float* __restrict__ hin, int b, int tid) {
    int lane = tid & 63, w = tid >> 6;
    int n = b * 4 + w;
    int deg = g_deg[n];
    int dg = deg < BST ? deg : BST;
    const int* bp = &g_bkt[n * BST];
    float s0 = 0.f, s1 = 0.f, s2 = 0.f, s3 = 0.f;
    float s4 = 0.f, s5 = 0.f, s6 = 0.f, s7 = 0.f;
    int i = 0;
    for (; i + 8 <= dg; i += 8) {
        int4 a = *(const int4*)&bp[i];
        int4 c = *(const int4*)&bp[i + 4];
        s0 += hin[a.x * Df + lane];
        s1 += hin[a.y * Df + lane];
        s2 += hin[a.z * Df + lane];
        s3 += hin[a.w * Df + lane];
        s4 += hin[c.x * Df + lane];
        s5 += hin[c.y * Df + lane];
        s6 += hin[c.z * Df + lane];
        s7 += hin[c.w * Df + lane];
    }
    for (; i < dg; i++) s0 += hin[bp[i] * Df + lane];
    float s = ((s0 + s1) + (s2 + s3)) + ((s4 + s5) + (s6 + s7));
    g_agg[n * Df + lane] = s / fmaxf((float)deg, 1.f);
}

// ---------------- tiled GEMM (64 nodes x 64 dims, K=128) ----------------
__device__ void gemm_tile(const float* __restrict__ hin, float* __restrict__ hout,
                          const float* __restrict__ W2, const float* __restrict__ bias,
                          int m0, int tid, char* smem) {
    float (*Xs)[68] = (float(*)[68])smem;
    float (*Wl)[64] = (float(*)[64])(smem + 8704);
    int tx = tid & 15, ty = tid >> 4;
    float acc[4][4];
#pragma unroll
    for (int i = 0; i < 4; i++)
#pragma unroll
        for (int j = 0; j < 4; j++) acc[i][j] = 0.f;

    for (int c = 0; c < 4; c++) {
        const float* src = (c < 2) ? hin : g_agg;
        int kb = (c & 1) * 32;
        int kbase = c * 32;
#pragma unroll
        for (int rep = 0; rep < 2; rep++) {
            int slot = tid + rep * 256;
            int m = slot >> 3, q = slot & 7;
            int n = m0 + m;
            float4 v = make_float4(0.f, 0.f, 0.f, 0.f);
            if (n < NN) v = *(const float4*)&src[n * Df + kb + q * 4];
            Xs[q * 4 + 0][m] = v.x; Xs[q * 4 + 1][m] = v.y;
            Xs[q * 4 + 2][m] = v.z; Xs[q * 4 + 3][m] = v.w;
            int k = slot >> 4, dq = slot & 15;
            *(float4*)&Wl[k][dq * 4] = *(const float4*)&W2[(kbase + k) * Df + dq * 4];
        }
        __syncthreads();
#pragma unroll
        for (int k = 0; k < 32; k++) {
            float4 x4 = *(const float4*)&Xs[k][ty * 4];
            float4 w4 = *(const float4*)&Wl[k][tx * 4];
            float xs[4] = {x4.x, x4.y, x4.z, x4.w};
            float ws[4] = {w4.x, w4.y, w4.z, w4.w};
#pragma unroll
            for (int i = 0; i < 4; i++)
#pragma unroll
                for (int j = 0; j < 4; j++) acc[i][j] += xs[i] * ws[j];
        }
        __syncthreads();
    }
    float4 b4 = *(const float4*)&bias[tx * 4];
    float bb[4] = {b4.x, b4.y, b4.z, b4.w};
#pragma unroll
    for (int i = 0; i < 4; i++) {
        int n = m0 + ty * 4 + i;
        if (n < NN) {
            float4 hv = *(const float4*)&hin[n * Df + tx * 4];
            float4 o;
            o.x = fmaxf(acc[i][0] + bb[0], 0.f) + hv.x;
            o.y = fmaxf(acc[i][1] + bb[1], 0.f) + hv.y;
            o.z = fmaxf(acc[i][2] + bb[2], 0.f) + hv.z;
            o.w = fmaxf(acc[i][3] + bb[3], 0.f) + hv.w;
            *(float4*)&hout[n * Df + tx * 4] = o;
        }
    }
}

// ---------------- delta1 (4 slots/vblock, wave per slot) ----------------
__device__ void delta1_blk(int rel, int tid, const int* __restrict__ removal,
                           const float* __restrict__ Ws, const float* __restrict__ Wn,
                           const float* __restrict__ bias, char* smem) {
    float* s_h = (float*)smem;                   // [4][Df]
    float* s_a = s_h + 4 * Df;
    int ri = rel >> 5, y = rel & 31;
    int lane = tid & 63, w = tid >> 6;
    int j = y * 4 + w;
    if (j >= g_n1[ri]) return;
    int v = g_list1[ri][j];
    int r = removal[ri];
    float p0s = 0.f, p1s = 0.f, p2s = 0.f, p3s = 0.f; int cnt = 0;
    if (v != r) {
        int deg = g_deg[v];
        int dg = deg < BST ? deg : BST;
        const int* bp = &g_bkt[v * BST];
        int i = 0;
        for (; i + 4 <= dg; i += 4) {
            int c0 = bp[i], c1 = bp[i + 1], c2 = bp[i + 2], c3 = bp[i + 3];
            const float* p0 = (c0 == r) ? g_zrow : &g_h0[c0 * Df];
            const float* p1 = (c1 == r) ? g_zrow : &g_h0[c1 * Df];
            const float* p2 = (c2 == r) ? g_zrow : &g_h0[c2 * Df];
            const float* p3 = (c3 == r) ? g_zrow : &g_h0[c3 * Df];
            p0s += p0[lane]; p1s += p1[lane]; p2s += p2[lane]; p3s += p3[lane];
            cnt += (c0 != r) + (c1 != r) + (c2 != r) + (c3 != r);
        }
        for (; i < dg; i++) {
            int c = bp[i];
            const float* p = (c == r) ? g_zrow : &g_h0[c * Df];
            p0s += p[lane]; cnt += (c != r);
        }
    }
    float aggd = (p0s + p1s) + (p2s + p3s);
    float hv = g_h0[v * Df + lane];
    s_h[w * Df + lane] = hv;
    s_a[w * Df + lane] = aggd / fmaxf((float)cnt, 1.f);
    float acc = bias[lane];
#pragma unroll 16
    for (int k = 0; k < Df; k++)
        acc += s_h[w * Df + k] * Ws[k * Df + lane] + s_a[w * Df + k] * Wn[k * Df + lane];
    g_d1[ri][j][lane] = fmaxf(acc, 0.f) + hv;
}

// ---------------- delta2 (4 slots/vblock, wave per slot) ----------------
__device__ void delta2_blk(int rel, int tid, const int* __restrict__ removal,
                           const float* __restrict__ Ws, const float* __restrict__ Wn,
                           const float* __restrict__ bias, char* smem) {
    float* s_h = (float*)smem;
    float* s_a = s_h + 4 * Df;
    int ri = rel >> 9, y = rel & 511;
    int lane = tid & 63, w = tid >> 6;
    int j = y * 4 + w;
    if (j >= g_n2[ri]) return;
    int v = g_list2[ri][j];
    int r = removal[ri];
    const int* mk1 = g_mark1[ri];
    float p0s = 0.f, p1s = 0.f, p2s = 0.f, p3s = 0.f; int cnt = 0;
    if (v != r) {
        int deg = g_deg[v];
        int dg = deg < BST ? deg : BST;
        const int* bp = &g_bkt[v * BST];
        int i = 0;
        for (; i + 4 <= dg; i += 4) {
            int c0 = bp[i], c1 = bp[i + 1], c2 = bp[i + 2], c3 = bp[i + 3];
            int m0 = mk1[c0], m1 = mk1[c1], m2 = mk1[c2], m3 = mk1[c3];
            const float* p0 = (c0 == r) ? g_zrow : (m0 > 0 ? &g_d1[ri][m0 - 1][0] : &g_h1b[c0 * Df]);
            const float* p1 = (c1 == r) ? g_zrow : (m1 > 0 ? &g_d1[ri][m1 - 1][0] : &g_h1b[c1 * Df]);
            const float* p2 = (c2 == r) ? g_zrow : (m2 > 0 ? &g_d1[ri][m2 - 1][0] : &g_h1b[c2 * Df]);
            const float* p3 = (c3 == r) ? g_zrow : (m3 > 0 ? &g_d1[ri][m3 - 1][0] : &g_h1b[c3 * Df]);
            p0s += p0[lane]; p1s += p1[lane]; p2s += p2[lane]; p3s += p3[lane];
            cnt += (c0 != r) + (c1 != r) + (c2 != r) + (c3 != r);
        }
        for (; i < dg; i++) {
            int c = bp[i];
            int m = mk1[c];
            const float* p = (c == r) ? g_zrow : (m > 0 ? &g_d1[ri][m - 1][0] : &g_h1b[c * Df]);
            p0s += p[lane]; cnt += (c != r);
        }
    }
    float aggd = (p0s + p1s) + (p2s + p3s);
    int mv = mk1[v];
    float hv = (mv > 0) ? g_d1[ri][mv - 1][lane] : g_h1b[v * Df + lane];
    s_h[w * Df + lane] = hv;
    s_a[w * Df + lane] = aggd / fmaxf((float)cnt, 1.f);
    float acc = bias[lane];
#pragma unroll 16
    for (int k = 0; k < Df; k++)
        acc += s_h[w * Df + k] * Ws[k * Df + lane] + s_a[w * Df + k] * Wn[k * Df + lane];
    g_d2[ri][j][lane] = fmaxf(acc, 0.f) + hv;
}

// ================= L1: init =================
__global__ void k_init(const float* __restrict__ coords, const float* __restrict__ We,
                       const float* __restrict__ be, const float* __restrict__ Ws0,
                       const float* __restrict__ Wn0, const float* __restrict__ Ws1,
                       const float* __restrict__ Wn1) {
    int i = blockIdx.x * 256 + threadIdx.x;
    if (i < NN * Df) {
        int n = i >> 6, d = i & 63;
        g_h0[i] = coords[2 * n] * We[d] + coords[2 * n + 1] * We[Df + d] + be[d];
    }
    if (i < NN) { g_deg[i] = 0; g_m1mask[i] = 0; g_m2mask[i] = 0; }
    if (i < Df) g_zrow[i] = 0.f;
    if (i < 8192) {
        int k = i >> 6, d = i & 63;
        g_W20[i] = (k < 64) ? Ws0[k * 64 + d] : Wn0[(k - 64) * 64 + d];
        g_W21[i] = (k < 64) ? Ws1[k * 64 + d] : Wn1[(k - 64) * 64 + d];
    }
}

// ================= L2: bucket fill + flag1 =================
__global__ void k_fillflag(const int* __restrict__ esrc, const int* __restrict__ edst,
                           const int* __restrict__ removal) {
    __shared__ int s_rem[RR];
    int tid = threadIdx.x;
    if (tid < RR) s_rem[tid] = removal[tid];
    __syncthreads();
    int e = blockIdx.x * 256 + tid;
    if (e < EE) {
        int s = esrc[e], d = edst[e];
        int p = atomicAdd(&g_deg[d], 1);
        if (p < BST) g_bkt[d * BST + p] = s;
        int m = 0;
#pragma unroll
        for (int ri = 0; ri < RR; ri++)
            if (s == s_rem[ri]) m |= (1 << ri);
        if (m) atomicOr(&g_m1mask[d], m);
    }
    if (blockIdx.x == 0 && tid < RR)
        atomicOr(&g_m1mask[removal[tid]], 1 << tid);
}

// ================= L3: agg0 | flag2-edges | flag2-self | compact1 =================
__global__ __launch_bounds__(256) void k_L3(const int* __restrict__ esrc,
                                            const int* __restrict__ edst) {
    int b = blockIdx.x, tid = threadIdx.x;
    if (b < NAGG) { agg8(g_h0, b, tid); return; }
    if (b < NAGG + NEDG) {
        int e = (b - NAGG) * 256 + tid;
        if (e < EE) {
            int m = g_m1mask[esrc[e]];
            if (m) atomicOr(&g_m2mask[edst[e]], m);
        }
        return;
    }
    if (b < NAGG + NEDG + NSLF) {
        int v = (b - NAGG - NEDG) * 256 + tid;
        if (v < NN) {
            int m = g_m1mask[v];
            if (m) atomicOr(&g_m2mask[v], m);
        }
        return;
    }
    int ri = b - NAGG - NEDG - NSLF;
    compact256(g_m1mask, ri, g_mark1[ri], g_list1[ri], &g_n1[ri], CAP1);
}

// ================= L4: gemm0 | delta1 | compact2 =================
__global__ __launch_bounds__(256) void k_L4(const int* __restrict__ removal,
        const float* __restrict__ Ws0, const float* __restrict__ Wn0,
        const float* __restrict__ b0) {
    __shared__ __align__(16) char smem[16896];
    int b = blockIdx.x, tid = threadIdx.x;
    if (b < NGEMM) { gemm_tile(g_h0, g_h1b, g_W20, b0, b * 64, tid, smem); return; }
    if (b < NGEMM + ND1B) { delta1_blk(b - NGEMM, tid, removal, Ws0, Wn0, b0, smem); return; }
    int ri = b - NGEMM - ND1B;
    compact256(g_m2mask, ri, g_mark2[ri], g_list2[ri], &g_n2[ri], CAP2);
}

// ================= L5: agg1 | delta2 =================
__global__ __launch_bounds__(256) void k_L5(const int* __restrict__ removal,
        const float* __restrict__ Ws1, const float* __restrict__ Wn1,
        const float* __restrict__ b1) {
    __shared__ __align__(16) char smem[2048];
    int b = blockIdx.x, tid = threadIdx.x;
    if (b < NAGG) { agg8(g_h1b, b, tid); return; }
    delta2_blk(b - NAGG, tid, removal, Ws1, Wn1, b1, smem);
}

// ================= L6: gemm1 =================
__global__ __launch_bounds__(256) void k_gemm1(const float* __restrict__ b1) {
    __shared__ __align__(16) char smem[16896];
    gemm_tile(g_h1b, g_h2b, g_W21, b1, blockIdx.x * 64, threadIdx.x, smem);
}

// ================= L7: score GEMM (64 edges x 64 dims per block) =================
__global__ __launch_bounds__(256) void k_score(const int* __restrict__ conn,
        const int* __restrict__ removal, const int* __restrict__ esrc,
        const int* __restrict__ edst, const float* __restrict__ We,
        const float* __restrict__ be, const float* __restrict__ Wsc,
        const float* __restrict__ bsc) {
    __shared__ const float* ptrs[128];
    __shared__ float Xs[32][68];
    __shared__ float Wl[32][64];
    __shared__ float su;
    int tid = threadIdx.x;
    int e0 = blockIdx.x * 64;
    int ri = e0 >> 9;

    if (tid < 64) {
        int e = conn[e0 + tid];
        int s = esrc[e], d = edst[e];
        int ms = g_mark2[ri][s], md = g_mark2[ri][d];
        ptrs[tid]      = (ms > 0) ? &g_d2[ri][ms - 1][0] : &g_h2b[s * Df];
        ptrs[64 + tid] = (md > 0) ? &g_d2[ri][md - 1][0] : &g_h2b[d * Df];
    } else if (tid < 128) {
        int lane = tid & 63;
        float up = g_h0[removal[ri] * Df + lane] * Wsc[lane];
#pragma unroll
        for (int off = 32; off > 0; off >>= 1) up += __shfl_xor(up, off, 64);
        if (lane == 0) su = up;
    }
    __syncthreads();

    int tx = tid & 15, ty = tid >> 4;
    float acc[4][4];
#pragma unroll
    for (int i = 0; i < 4; i++)
#pragma unroll
        for (int j = 0; j < 4; j++) acc[i][j] = 0.f;

    for (int c = 0; c < 4; c++) {
        int kb = (c & 1) * 32;
#pragma unroll
        for (int rep = 0; rep < 2; rep++) {
            int slot = tid + rep * 256;
            int m = slot >> 3, q = slot & 7;
            const float* p = ((c < 2) ? ptrs[m] : ptrs[64 + m]) + kb + q * 4;
            float4 v = *(const float4*)p;
            Xs[q * 4 + 0][m] = v.x; Xs[q * 4 + 1][m] = v.y;
            Xs[q * 4 + 2][m] = v.z; Xs[q * 4 + 3][m] = v.w;
            int k = slot >> 4, dq = slot & 15;
            *(float4*)&Wl[k][dq * 4] = *(const float4*)&We[(c * 32 + k) * Df + dq * 4];
        }
        __syncthreads();
#pragma unroll
        for (int k = 0; k < 32; k++) {
            float4 x4 = *(const float4*)&Xs[k][ty * 4];
            float4 w4 = *(const float4*)&Wl[k][tx * 4];
            float xs[4] = {x4.x, x4.y, x4.z, x4.w};
            float ws[4] = {w4.x, w4.y, w4.z, w4.w};
#pragma unroll
            for (int i = 0; i < 4; i++)
#pragma unroll
                for (int j = 0; j < 4; j++) acc[i][j] += xs[i] * ws[j];
        }
        __syncthreads();
    }

    float4 be4 = *(const float4*)&be[tx * 4];
    float4 w2  = *(const float4*)&Wsc[Df + tx * 4];
    float bb[4] = {be4.x, be4.y, be4.z, be4.w};
    float ww[4] = {w2.x, w2.y, w2.z, w2.w};
    float sb = su + bsc[0];
#pragma unroll
    for (int i = 0; i < 4; i++) {
        float part = 0.f;
#pragma unroll
        for (int j = 0; j < 4; j++) part += fmaxf(acc[i][j] + bb[j], 0.f) * ww[j];
#pragma unroll
        for (int off = 1; off < 16; off <<= 1) part += __shfl_xor(part, off, 64);
        if (tx == 0) g_score[e0 + ty * 4 + i] = part + sb;
    }
}

// ================= L8: softmax =================
__global__ void k_softmax(float* __restrict__ out) {
    int r = blockIdx.x;
    int t = threadIdx.x;
    float v0 = g_score[r * CC + t];
    float v1 = g_score[r * CC + 256 + t];
    __shared__ float red[256];
    red[t] = fmaxf(v0, v1);
    __syncthreads();
    for (int off = 128; off > 0; off >>= 1) {
        if (t < off) red[t] = fmaxf(red[t], red[t + off]);
        __syncthreads();
    }
    float mx = red[0];
    __syncthreads();
    float e0 = expf(v0 - mx), e1 = expf(v1 - mx);
    red[t] = e0 + e1;
    __syncthreads();
    for (int off = 128; off > 0; off >>= 1) {
        if (t < off) red[t] += red[t + off];
        __syncthreads();
    }
    float inv = 1.f / red[0];
    out[r * CC + t] = e0 * inv;
    out[r * CC + 256 + t] = e1 * inv;
}

extern "C" void kernel_launch(void* const* d_in, const int* in_sizes, int n_in,
                              void* d_out, int out_size, void* d_ws, size_t ws_size,
                              hipStream_t stream) {
    const float* coords   = (const float*)d_in[0];
    const float* W_emb    = (const float*)d_in[1];
    const float* b_emb    = (const float*)d_in[2];
    const float* W_self0  = (const float*)d_in[3];
    const float* W_neigh0 = (const float*)d_in[4];
    const float* b_gnn0   = (const float*)d_in[5];
    const float* W_self1  = (const float*)d_in[6];
    const float* W_neigh1 = (const float*)d_in[7];
    const float* b_gnn1   = (const float*)d_in[8];
    const float* W_edge   = (const float*)d_in[9];
    const float* b_edge   = (const float*)d_in[10];
    const float* W_score  = (const float*)d_in[11];
    const float* b_score  = (const float*)d_in[12];
    const int* esrc       = (const int*)d_in[13];
    const int* edst       = (const int*)d_in[14];
    const int* removal    = (const int*)d_in[15];
    const int* conn       = (const int*)d_in[16];

    k_init<<<2500, 256, 0, stream>>>(coords, W_emb, b_emb, W_self0, W_neigh0,
                                     W_self1, W_neigh1);
    k_fillflag<<<NEDG, 256, 0, stream>>>(esrc, edst, removal);
    k_L3<<<NAGG + NEDG + NSLF + RR, 256, 0, stream>>>(esrc, edst);
    k_L4<<<NGEMM + ND1B + RR, 256, 0, stream>>>(removal, W_self0, W_neigh0, b_gnn0);
    k_L5<<<NAGG + ND2B, 256, 0, stream>>>(removal, W_self1, W_neigh1, b_gnn1);
    k_gemm1<<<NGEMM, 256, 0, stream>>>(b_gnn1);
    k_score<<<RR * CC / 64, 256, 0, stream>>>(conn, removal, esrc, edst,
                                              W_edge, b_edge, W_score, b_score);
    k_softmax<<<RR, 256, 0, stream>>>((float*)d_out);
}